// Round 3
// baseline (353.067 us; speedup 1.0000x reference)
//
#include <hip/hip_runtime.h>

// ---------- types / helpers ----------
using bf8v = __bf16 __attribute__((ext_vector_type(8)));
using s4v  = short  __attribute__((ext_vector_type(4)));
using f4v  = float  __attribute__((ext_vector_type(4)));

#define L2E 1.44269504088896340f

__device__ __forceinline__ float ex2(float x){ float r; asm("v_exp_f32 %0, %1" : "=v"(r) : "v"(x)); return r; }
__device__ __forceinline__ float rcp_(float x){ float r; asm("v_rcp_f32 %0, %1" : "=v"(r) : "v"(x)); return r; }
__device__ __forceinline__ float sigm(float x){ return rcp_(1.0f + ex2(-L2E*x)); }
__device__ __forceinline__ float tanh_(float x){ return 1.0f - 2.0f*rcp_(1.0f + ex2(2.0f*L2E*x)); }
__device__ __forceinline__ short f2bf(float x){ return __builtin_bit_cast(short, (__bf16)x); }
__device__ __forceinline__ f4v splat4(float v){ f4v r = {v,v,v,v}; return r; }
__device__ __forceinline__ f4v mfma16(bf8v a, bf8v b, f4v c){
  return __builtin_amdgcn_mfma_f32_16x16x32_bf16(a, b, c, 0, 0, 0);
}

// ---------- prep: fold W2/b2, fragment-ize weights, posenc, x fragments ----------
__global__ void prep_kernel(
    const float* __restrict__ x,
    const float* __restrict__ W_emb, const float* __restrict__ b_emb,
    const float* __restrict__ W_ih,  const float* __restrict__ W_hh,
    const float* __restrict__ b_ih,
    const float* __restrict__ Wg1,   const float* __restrict__ Wn1,
    const float* __restrict__ Wn2,
    const float* __restrict__ bg1,   const float* __restrict__ bn1,
    short* __restrict__ bhhf, short* __restrict__ wcf, short* __restrict__ wn2f,
    short* __restrict__ w2f, float* __restrict__ b2, float* __restrict__ pe,
    float* __restrict__ bc, short* __restrict__ xfrag)
{
  int i = blockIdx.x*256 + threadIdx.x;
  if (i < 49152){ // W_hh fragments [kb4][nt24][lane][e]; B[k][n] = W_hh[n][k]
    int e = i&7, lane=(i>>3)&63, r=i>>9; int nt=r%24, kb=r/24;
    int k = kb*32 + ((lane>>4)<<3) + e;
    int n = nt*16 + (lane&15);
    bhhf[i] = f2bf(W_hh[n*128 + k]);
    return;
  }
  i -= 49152;
  if (i < 40960){ // Wc = [Wg1 | Wn1] fragments [kb5][nt16][lane][e], K padded to 160
    int e=i&7, lane=(i>>3)&63, r=i>>9; int nt=r%16, kb=r/16;
    int k = kb*32 + ((lane>>4)<<3) + e; int n = nt*16 + (lane&15);
    float v = 0.f;
    if (k < 134) v = (n < 128) ? Wg1[k*128 + n] : Wn1[k*128 + (n-128)];
    wcf[i] = f2bf(v);
    return;
  }
  i -= 40960;
  if (i < 16384){ // Wn2 fragments [kb4][nt8][lane][e]
    int e=i&7, lane=(i>>3)&63, r=i>>9; int nt=r%8, kb=r/8;
    int k = kb*32 + ((lane>>4)<<3) + e; int n = nt*16 + (lane&15);
    wn2f[i] = f2bf(Wn2[k*128 + n]);
    return;
  }
  i -= 16384;
  if (i < 12288){ // W2 = W_emb @ W_ih^T fragments [nt24][lane][e], K=32 (rows>=6 zero)
    int e=i&7, lane=(i>>3)&63, nt=i>>9;
    int k = ((lane>>4)<<3) + e; int n = nt*16 + (lane&15);
    float v = 0.f;
    if (k < 6){
      const float* we = W_emb + k*128; const float* wi = W_ih + n*128;
      float s = 0.f;
      for (int h2=0; h2<128; ++h2) s += we[h2]*wi[h2];
      v = s;
    }
    w2f[i] = f2bf(v);
    return;
  }
  i -= 12288;
  if (i < 384){ // b2 = b_ih + b_emb @ W_ih^T
    float s = b_ih[i]; const float* wi = W_ih + i*128;
    for (int h2=0; h2<128; ++h2) s += b_emb[h2]*wi[h2];
    b2[i] = s;
    return;
  }
  i -= 384;
  if (i < 10240){ // posenc [64][160] fp32 (cols>=134 zero)
    int t = i/160, k = i%160;
    float v = 0.f;
    if (k < 134){
      float fr = expf(-(float)(k & ~1) * 9.210340371976184f / 134.f);
      float a = (float)t * fr;
      v = (k&1) ? cosf(a) : sinf(a);
    }
    pe[i] = v;
    return;
  }
  i -= 10240;
  if (i < 256){ bc[i] = (i < 128) ? bg1[i] : bn1[i-128]; return; }
  i -= 256;
  if (i < 524288){ // xfrag [grp512][t64][r16][8 bf16]: slots 0..5 = x[grp*16+r][t][:], 6,7 = 0
    int r = i & 15, t = (i>>4)&63, grp = i>>10;
    const float* xr = x + ((size_t)(grp*16 + r)*64 + t)*6;
    s4v lo, hi;
    lo[0]=f2bf(xr[0]); lo[1]=f2bf(xr[1]); lo[2]=f2bf(xr[2]); lo[3]=f2bf(xr[3]);
    hi[0]=f2bf(xr[4]); hi[1]=f2bf(xr[5]); hi[2]=0; hi[3]=0;
    *reinterpret_cast<s4v*>(xfrag + (size_t)i*8)     = lo;
    *reinterpret_cast<s4v*>(xfrag + (size_t)i*8 + 4) = hi;
    return;
  }
}

// ---------- GRU: 32 seqs/block as 2 streams x 16; 8 waves; 256 blocks (1/CU) ----------
// Per-wave ILP: two independent streams interleave MFMA and VALU/trans chains.
__global__ __launch_bounds__(512, 2) void gru_kernel(
    const short* __restrict__ xfrag,   // [512][64][16][8]
    const short* __restrict__ bhhf,    // [4][24][64][8]
    const short* __restrict__ w2f,     // [24][64][8]
    const float* __restrict__ b2,      // 384
    const float* __restrict__ b_hh,    // 384
    float* __restrict__ h_out)         // (8192,128)
{
  __shared__ alignas(16) short h_lds[2][2][16*128];  // [stream][dbuf], XOR-swizzled rows
  const int tid = threadIdx.x;
  const int w = tid >> 6;
  const int lane = tid & 63;
  const int l15 = lane & 15, lhi = lane >> 4;
  const int blk = blockIdx.x;

  for (int i = tid; i < 16*128; i += 512){ h_lds[0][0][i] = 0; h_lds[1][0][i] = 0; }

  // hoisted B fragments + biases
  bf8v bhh[4][3]; bf8v w2v[3];
  float b2v[3], bhv[3];
  #pragma unroll
  for (int g = 0; g < 3; ++g){
    int nt = g*8 + w;
    w2v[g] = *reinterpret_cast<const bf8v*>(w2f + ((nt*64 + lane)<<3));
    #pragma unroll
    for (int kb = 0; kb < 4; ++kb)
      bhh[kb][g] = *reinterpret_cast<const bf8v*>(bhhf + (((kb*24 + nt)*64 + lane)<<3));
    int col = nt*16 + l15;
    b2v[g] = b2[col]; bhv[g] = b_hh[col];
  }
  float hr0[4] = {0.f,0.f,0.f,0.f};
  float hr1[4] = {0.f,0.f,0.f,0.f};
  __syncthreads();

  const short* xf0 = xfrag + (size_t)(2*blk  )*8192 + l15*8;
  const short* xf1 = xfrag + (size_t)(2*blk+1)*8192 + l15*8;
  const int sw_r = (l15 & 7) << 4;

  bf8v ax0 = *reinterpret_cast<const bf8v*>(xf0);
  bf8v ax1 = *reinterpret_cast<const bf8v*>(xf1);

#define GSTEP(P, T)                                                           \
  {                                                                           \
    int tn = (T) + 1; if (tn > 63) tn = 63;                                   \
    bf8v axn0 = *reinterpret_cast<const bf8v*>(xf0 + tn*128);                 \
    bf8v axn1 = *reinterpret_cast<const bf8v*>(xf1 + tn*128);                 \
    bf8v ah0[4], ah1[4];                                                      \
    _Pragma("unroll")                                                         \
    for (int kb = 0; kb < 4; ++kb){                                           \
      int off = l15*256 + ((kb*64 + lhi*16) ^ sw_r);                          \
      ah0[kb] = *reinterpret_cast<const bf8v*>((const char*)h_lds[0][P] + off); \
      ah1[kb] = *reinterpret_cast<const bf8v*>((const char*)h_lds[1][P] + off); \
    }                                                                         \
    f4v xg0[3], gh0[3], xg1[3], gh1[3];                                       \
    _Pragma("unroll")                                                         \
    for (int g = 0; g < 3; ++g){                                              \
      xg0[g] = splat4(b2v[g]); xg0[g] = mfma16(ax0, w2v[g], xg0[g]);          \
      xg1[g] = splat4(b2v[g]); xg1[g] = mfma16(ax1, w2v[g], xg1[g]);          \
      gh0[g] = splat4(bhv[g]); gh1[g] = splat4(bhv[g]);                       \
      _Pragma("unroll")                                                       \
      for (int kb = 0; kb < 4; ++kb){                                         \
        gh0[g] = mfma16(ah0[kb], bhh[kb][g], gh0[g]);                         \
        gh1[g] = mfma16(ah1[kb], bhh[kb][g], gh1[g]);                         \
      }                                                                       \
    }                                                                         \
    _Pragma("unroll")                                                         \
    for (int r = 0; r < 4; ++r){                                              \
      int s = lhi*4 + r;                                                      \
      int woff = s*256 + (((w*16 + l15)*2) ^ ((s&7)<<4));                     \
      { float rg = sigm(xg0[0][r] + gh0[0][r]);                               \
        float zg = sigm(xg0[1][r] + gh0[1][r]);                               \
        float ng = tanh_(xg0[2][r] + rg*gh0[2][r]);                           \
        float hv = ng + zg*(hr0[r] - ng); hr0[r] = hv;                        \
        *(short*)((char*)h_lds[0][P^1] + woff) = f2bf(hv); }                  \
      { float rg = sigm(xg1[0][r] + gh1[0][r]);                               \
        float zg = sigm(xg1[1][r] + gh1[1][r]);                               \
        float ng = tanh_(xg1[2][r] + rg*gh1[2][r]);                           \
        float hv = ng + zg*(hr1[r] - ng); hr1[r] = hv;                        \
        *(short*)((char*)h_lds[1][P^1] + woff) = f2bf(hv); }                  \
    }                                                                         \
    ax0 = axn0; ax1 = axn1;                                                   \
    __syncthreads();                                                          \
  }

  for (int tt = 0; tt < 32; ++tt){
    GSTEP(0, 2*tt);
    GSTEP(1, 2*tt + 1);
  }
#undef GSTEP

  #pragma unroll
  for (int r = 0; r < 4; ++r){
    int s = lhi*4 + r;
    h_out[(size_t)((2*blk  )*16 + s)*128 + w*16 + l15] = hr0[r];
    h_out[(size_t)((2*blk+1)*16 + s)*128 + w*16 + l15] = hr1[r];
  }
}

// ---------- feats: one seq (64 rows) per block; gate+val GEMMs + segment partials ----------
// A1 stride 320B, 4-row XOR swizzle; A2 (256B stride, 8-row swizzle) aliased into A1 region.
__global__ __launch_bounds__(256, 6) void feats_kernel(
    const float* __restrict__ x, const float* __restrict__ h_out,
    const float* __restrict__ pe,
    const short* __restrict__ wcf, const short* __restrict__ wn2f,
    const float* __restrict__ bc, const float* __restrict__ Wg2,
    const float* __restrict__ bg2, const float* __restrict__ bn2,
    float* __restrict__ partials)  // [8192][130] = {max, sumE, sumEV[128]}
{
  __shared__ alignas(16) char AB[64*320];     // A1: 64 x 320B | A2: 64 x 256B (aliased)
  __shared__ alignas(16) float hb[160];       // zero-padded h vector
  __shared__ float gp[2][64];
  __shared__ float gate_arr[64];

  const int tid = threadIdx.x;
  const int w = tid >> 6;
  const int lane = tid & 63;
  const int l15 = lane & 15, lhi = lane >> 4;
  const int seq = blockIdx.x;

  if (tid < 160) hb[tid] = (tid >= 6 && tid < 134) ? h_out[(size_t)seq*128 + tid - 6] : 0.f;
  __syncthreads();

  { // build A1: row m = tid>>2, quarter q = tid&3 (40 cols each)
    int m = tid >> 2, q = tid & 3, k0 = q*40;
    float xr8[8] = {0.f,0.f,0.f,0.f,0.f,0.f,0.f,0.f};
    if (q == 0){
      const float* xr = x + (size_t)(seq*64 + m)*6;
      #pragma unroll
      for (int j = 0; j < 6; ++j) xr8[j] = xr[j];
    }
    const float* per = pe + m*160 + k0;
    const f4v* hb4 = reinterpret_cast<const f4v*>(hb + k0);
    int swm = (m & 3) << 4;
    #pragma unroll
    for (int j = 0; j < 10; ++j){
      f4v v = hb4[j];
      f4v p4 = *reinterpret_cast<const f4v*>(per + 4*j);
      v += p4;
      if (j < 2){
        v[0] += xr8[4*j+0]; v[1] += xr8[4*j+1];
        v[2] += xr8[4*j+2]; v[3] += xr8[4*j+3];
      }
      s4v o;
      #pragma unroll
      for (int c = 0; c < 4; ++c) o[c] = f2bf(v[c]);
      int off = m*320 + (((k0 + 4*j)*2) ^ swm);
      *reinterpret_cast<s4v*>(AB + off) = o;
    }
  }
  __syncthreads();

  // GEMM1: hidden(64x256) = A1(64x160) @ Wc(160x256) + bc ; wave w -> nt ntb..ntb+3
  const int ntb = w*4;
  float bcv[4];
  #pragma unroll
  for (int i=0;i<4;++i) bcv[i] = bc[(ntb+i)*16 + l15];
  f4v acc[4][4];
  #pragma unroll
  for (int mt=0;mt<4;++mt)
    #pragma unroll
    for (int i=0;i<4;++i) acc[mt][i] = splat4(bcv[i]);
  #pragma unroll
  for (int kb = 0; kb < 5; ++kb){
    bf8v a[4];
    #pragma unroll
    for (int mt=0;mt<4;++mt){
      int row = l15 + 16*mt;
      int off = row*320 + ((kb*64 + lhi*16) ^ ((row&3)<<4));
      a[mt] = *reinterpret_cast<const bf8v*>(AB + off);
    }
    bf8v b[4];
    #pragma unroll
    for (int i=0;i<4;++i)
      b[i] = *reinterpret_cast<const bf8v*>(wcf + (((kb*16 + ntb + i)*64 + lane)<<3));
    #pragma unroll
    for (int mt=0;mt<4;++mt)
      #pragma unroll
      for (int i=0;i<4;++i) acc[mt][i] = mfma16(a[mt], b[i], acc[mt][i]);
  }
  __syncthreads();   // all A1 reads complete (A2 will overwrite this region)

  // phase 2: waves 0,1 -> gate partials (in-wave reduce); waves 2,3 -> silu into A2
  if (w < 2){
    float wg2v[4];
    #pragma unroll
    for (int i=0;i<4;++i) wg2v[i] = Wg2[(ntb+i)*16 + l15];
    #pragma unroll
    for (int mt=0;mt<4;++mt)
      #pragma unroll
      for (int r=0;r<4;++r){
        float p = 0.f;
        #pragma unroll
        for (int i=0;i<4;++i){ float v = acc[mt][i][r]; p += v*sigm(v)*wg2v[i]; }
        p += __shfl_xor(p, 1); p += __shfl_xor(p, 2);
        p += __shfl_xor(p, 4); p += __shfl_xor(p, 8);
        if (l15 == 0) gp[w][mt*16 + lhi*4 + r] = p;
      }
  } else {
    #pragma unroll
    for (int mt=0;mt<4;++mt)
      #pragma unroll
      for (int i=0;i<4;++i)
        #pragma unroll
        for (int r=0;r<4;++r){
          float v = acc[mt][i][r]; float s = v*sigm(v);
          int row = mt*16 + lhi*4 + r;
          int colb = (((w-2)*4 + i)*16 + l15)*2;
          int off = row*256 + (colb ^ ((row&7)<<4));
          *(short*)(AB + off) = f2bf(s);
        }
  }
  __syncthreads();   // A2 + gp visible

  if (tid < 64) gate_arr[tid] = bg2[0] + gp[0][tid] + gp[1][tid];

  // GEMM2: val(64x128) = A2(64x128) @ Wn2 + bn2 ; wave w -> nt2 {2w,2w+1}
  const int nt2b = w*2;
  float bn2v[2];
  #pragma unroll
  for (int i=0;i<2;++i) bn2v[i] = bn2[(nt2b+i)*16 + l15];
  f4v acc2[4][2];
  #pragma unroll
  for (int mt=0;mt<4;++mt)
    #pragma unroll
    for (int i=0;i<2;++i) acc2[mt][i] = splat4(bn2v[i]);
  #pragma unroll
  for (int kb = 0; kb < 4; ++kb){
    bf8v a2f[4];
    #pragma unroll
    for (int mt=0;mt<4;++mt){
      int row = l15 + 16*mt;
      int off = row*256 + ((kb*64 + lhi*16) ^ ((row&7)<<4));
      a2f[mt] = *reinterpret_cast<const bf8v*>(AB + off);
    }
    bf8v b2f[2];
    #pragma unroll
    for (int i=0;i<2;++i)
      b2f[i] = *reinterpret_cast<const bf8v*>(wn2f + (((kb*8 + nt2b + i)*64 + lane)<<3));
    #pragma unroll
    for (int mt=0;mt<4;++mt)
      #pragma unroll
      for (int i=0;i<2;++i) acc2[mt][i] = mfma16(a2f[mt], b2f[i], acc2[mt][i]);
  }
  __syncthreads();  // gate_arr ready

  // phase 4: block-local softmax partials (exact flash combine)
  float g = gate_arr[lane];
  float M = g;
  #pragma unroll
  for (int d=1; d<64; d<<=1) M = fmaxf(M, __shfl_xor(M, d));
  float e = ex2((g - M)*L2E);
  float sE = e;
  #pragma unroll
  for (int d=1; d<64; d<<=1) sE += __shfl_xor(sE, d);
  float ev0 = 0.f, ev1 = 0.f;
  #pragma unroll
  for (int mt=0;mt<4;++mt)
    #pragma unroll
    for (int r=0;r<4;++r){
      int row = mt*16 + lhi*4 + r;
      float wm = ex2((gate_arr[row] - M)*L2E);
      ev0 += wm*acc2[mt][0][r];
      ev1 += wm*acc2[mt][1][r];
    }
  ev0 += __shfl_xor(ev0, 16); ev0 += __shfl_xor(ev0, 32);
  ev1 += __shfl_xor(ev1, 16); ev1 += __shfl_xor(ev1, 32);

  float* pb = partials + (size_t)seq*130;
  if (tid == 0){ pb[0] = M; pb[1] = sE; }
  if (lane < 16){
    pb[2 + (nt2b+0)*16 + lane] = ev0;
    pb[2 + (nt2b+1)*16 + lane] = ev1;
  }
}

// ---------- combine: merge 64 partials per batch ----------
__global__ void combine_kernel(const float* __restrict__ partials, float* __restrict__ out)
{
  int b = blockIdx.x; int j = threadIdx.x;  // 128 threads
  const float* pb = partials + (size_t)b*64*130;
  float M = -3.0e38f;
  for (int p = 0; p < 64; ++p) M = fmaxf(M, pb[p*130]);
  float num = 0.f, den = 0.f;
  for (int p = 0; p < 64; ++p){
    float wm = ex2((pb[p*130] - M)*L2E);
    den += wm * pb[p*130 + 1];
    num += wm * pb[p*130 + 2 + j];
  }
  out[b*128 + j] = num / den;
}

// ---------- host ----------
extern "C" void kernel_launch(void* const* d_in, const int* in_sizes, int n_in,
                              void* d_out, int out_size, void* d_ws, size_t ws_size,
                              hipStream_t stream) {
  (void)in_sizes; (void)n_in; (void)out_size; (void)ws_size;
  const float* x     = (const float*)d_in[0];
  const float* W_emb = (const float*)d_in[1];
  const float* b_emb = (const float*)d_in[2];
  const float* W_ih  = (const float*)d_in[3];
  const float* W_hh  = (const float*)d_in[4];
  const float* b_ih  = (const float*)d_in[5];
  const float* b_hh  = (const float*)d_in[6];
  const float* Wg1   = (const float*)d_in[7];
  const float* bg1   = (const float*)d_in[8];
  const float* Wg2   = (const float*)d_in[9];
  const float* bg2   = (const float*)d_in[10];
  const float* Wn1   = (const float*)d_in[11];
  const float* bn1   = (const float*)d_in[12];
  const float* Wn2   = (const float*)d_in[13];
  const float* bn2   = (const float*)d_in[14];

  char* p = (char*)d_ws;
  short* bhhf = (short*)p; p += 98304;
  short* wcf  = (short*)p; p += 81920;
  short* wn2f = (short*)p; p += 32768;
  short* w2f  = (short*)p; p += 24576;
  float* b2   = (float*)p; p += 1536;
  float* pe   = (float*)p; p += 40960;
  float* bc   = (float*)p; p += 1024;
  short* xfrag = (short*)p; p += (size_t)524288*8*2;     // 8.4 MB
  float* h_out    = (float*)p; p += (size_t)8192*128*4;
  float* partials = (float*)p; p += (size_t)8192*130*4;

  prep_kernel<<<2555, 256, 0, stream>>>(x, W_emb, b_emb, W_ih, W_hh, b_ih,
                                        Wg1, Wn1, Wn2, bg1, bn1,
                                        bhhf, wcf, wn2f, w2f, b2, pe, bc, xfrag);
  gru_kernel<<<256, 512, 0, stream>>>(xfrag, bhhf, w2f, b2, b_hh, h_out);
  feats_kernel<<<8192, 256, 0, stream>>>(x, h_out, pe, wcf, wn2f, bc, Wg2, bg2, bn2, partials);
  combine_kernel<<<128, 128, 0, stream>>>(partials, (float*)d_out);
}

// Round 4
// 193.277 us; speedup vs baseline: 1.8267x; 1.8267x over previous
//
#include <hip/hip_runtime.h>

// ---------- types / helpers ----------
using bf8v = __bf16 __attribute__((ext_vector_type(8)));
using s4v  = short  __attribute__((ext_vector_type(4)));
using f4v  = float  __attribute__((ext_vector_type(4)));

#define L2E 1.44269504088896340f

__device__ __forceinline__ float ex2(float x){ float r; asm("v_exp_f32 %0, %1" : "=v"(r) : "v"(x)); return r; }
__device__ __forceinline__ float rcp_(float x){ float r; asm("v_rcp_f32 %0, %1" : "=v"(r) : "v"(x)); return r; }
__device__ __forceinline__ float sigm(float x){ return rcp_(1.0f + ex2(-L2E*x)); }
__device__ __forceinline__ float tanh_(float x){ return 1.0f - 2.0f*rcp_(1.0f + ex2(2.0f*L2E*x)); }
__device__ __forceinline__ short f2bf(float x){ return __builtin_bit_cast(short, (__bf16)x); }
__device__ __forceinline__ f4v splat4(float v){ f4v r = {v,v,v,v}; return r; }
__device__ __forceinline__ f4v mfma16(bf8v a, bf8v b, f4v c){
  return __builtin_amdgcn_mfma_f32_16x16x32_bf16(a, b, c, 0, 0, 0);
}

// ---------- prep: fold W2/b2, fragment-ize weights, posenc, x fragments ----------
__global__ void prep_kernel(
    const float* __restrict__ x,
    const float* __restrict__ W_emb, const float* __restrict__ b_emb,
    const float* __restrict__ W_ih,  const float* __restrict__ W_hh,
    const float* __restrict__ b_ih,
    const float* __restrict__ Wg1,   const float* __restrict__ Wn1,
    const float* __restrict__ Wn2,
    const float* __restrict__ bg1,   const float* __restrict__ bn1,
    short* __restrict__ bhhf, short* __restrict__ wcf, short* __restrict__ wn2f,
    short* __restrict__ w2f, float* __restrict__ b2, float* __restrict__ pe,
    float* __restrict__ bc, short* __restrict__ xfrag)
{
  int i = blockIdx.x*256 + threadIdx.x;
  if (i < 49152){ // W_hh fragments [kb4][nt24][lane][e]; B[k][n] = W_hh[n][k]
    int e = i&7, lane=(i>>3)&63, r=i>>9; int nt=r%24, kb=r/24;
    int k = kb*32 + ((lane>>4)<<3) + e;
    int n = nt*16 + (lane&15);
    bhhf[i] = f2bf(W_hh[n*128 + k]);
    return;
  }
  i -= 49152;
  if (i < 40960){ // Wc = [Wg1 | Wn1] fragments [kb5][nt16][lane][e], K padded to 160
    int e=i&7, lane=(i>>3)&63, r=i>>9; int nt=r%16, kb=r/16;
    int k = kb*32 + ((lane>>4)<<3) + e; int n = nt*16 + (lane&15);
    float v = 0.f;
    if (k < 134) v = (n < 128) ? Wg1[k*128 + n] : Wn1[k*128 + (n-128)];
    wcf[i] = f2bf(v);
    return;
  }
  i -= 40960;
  if (i < 16384){ // Wn2 fragments [kb4][nt8][lane][e]
    int e=i&7, lane=(i>>3)&63, r=i>>9; int nt=r%8, kb=r/8;
    int k = kb*32 + ((lane>>4)<<3) + e; int n = nt*16 + (lane&15);
    wn2f[i] = f2bf(Wn2[k*128 + n]);
    return;
  }
  i -= 16384;
  if (i < 12288){ // W2 = W_emb @ W_ih^T fragments [nt24][lane][e], K=32 (rows>=6 zero)
    int e=i&7, lane=(i>>3)&63, nt=i>>9;
    int k = ((lane>>4)<<3) + e; int n = nt*16 + (lane&15);
    float v = 0.f;
    if (k < 6){
      const float* we = W_emb + k*128; const float* wi = W_ih + n*128;
      float s = 0.f;
      for (int h2=0; h2<128; ++h2) s += we[h2]*wi[h2];
      v = s;
    }
    w2f[i] = f2bf(v);
    return;
  }
  i -= 12288;
  if (i < 384){ // b2 = b_ih + b_emb @ W_ih^T
    float s = b_ih[i]; const float* wi = W_ih + i*128;
    for (int h2=0; h2<128; ++h2) s += b_emb[h2]*wi[h2];
    b2[i] = s;
    return;
  }
  i -= 384;
  if (i < 10240){ // posenc [64][160] fp32 (cols>=134 zero)
    int t = i/160, k = i%160;
    float v = 0.f;
    if (k < 134){
      float fr = expf(-(float)(k & ~1) * 9.210340371976184f / 134.f);
      float a = (float)t * fr;
      v = (k&1) ? cosf(a) : sinf(a);
    }
    pe[i] = v;
    return;
  }
  i -= 10240;
  if (i < 256){ bc[i] = (i < 128) ? bg1[i] : bn1[i-128]; return; }
  i -= 256;
  if (i < 524288){ // xfrag [grp512][t64][r16][8 bf16]: slots 0..5 = x[grp*16+r][t][:], 6,7 = 0
    int r = i & 15, t = (i>>4)&63, grp = i>>10;
    const float* xr = x + ((size_t)(grp*16 + r)*64 + t)*6;
    s4v lo, hi;
    lo[0]=f2bf(xr[0]); lo[1]=f2bf(xr[1]); lo[2]=f2bf(xr[2]); lo[3]=f2bf(xr[3]);
    hi[0]=f2bf(xr[4]); hi[1]=f2bf(xr[5]); hi[2]=0; hi[3]=0;
    *reinterpret_cast<s4v*>(xfrag + (size_t)i*8)     = lo;
    *reinterpret_cast<s4v*>(xfrag + (size_t)i*8 + 4) = hi;
    return;
  }
}

// ---------- GRU: 32 seqs/block as 2 streams x 16; 8 waves; 256 blocks (1/CU) ----------
// Per-wave ILP: two independent streams interleave MFMA and VALU/trans chains.
__global__ __launch_bounds__(512, 2) void gru_kernel(
    const short* __restrict__ xfrag,   // [512][64][16][8]
    const short* __restrict__ bhhf,    // [4][24][64][8]
    const short* __restrict__ w2f,     // [24][64][8]
    const float* __restrict__ b2,      // 384
    const float* __restrict__ b_hh,    // 384
    float* __restrict__ h_out)         // (8192,128)
{
  __shared__ alignas(16) short h_lds[2][2][16*128];  // [stream][dbuf], XOR-swizzled rows
  const int tid = threadIdx.x;
  const int w = tid >> 6;
  const int lane = tid & 63;
  const int l15 = lane & 15, lhi = lane >> 4;
  const int blk = blockIdx.x;

  for (int i = tid; i < 16*128; i += 512){ h_lds[0][0][i] = 0; h_lds[1][0][i] = 0; }

  // hoisted B fragments + biases
  bf8v bhh[4][3]; bf8v w2v[3];
  float b2v[3], bhv[3];
  #pragma unroll
  for (int g = 0; g < 3; ++g){
    int nt = g*8 + w;
    w2v[g] = *reinterpret_cast<const bf8v*>(w2f + ((nt*64 + lane)<<3));
    #pragma unroll
    for (int kb = 0; kb < 4; ++kb)
      bhh[kb][g] = *reinterpret_cast<const bf8v*>(bhhf + (((kb*24 + nt)*64 + lane)<<3));
    int col = nt*16 + l15;
    b2v[g] = b2[col]; bhv[g] = b_hh[col];
  }
  float hr0[4] = {0.f,0.f,0.f,0.f};
  float hr1[4] = {0.f,0.f,0.f,0.f};
  __syncthreads();

  const short* xf0 = xfrag + (size_t)(2*blk  )*8192 + l15*8;
  const short* xf1 = xfrag + (size_t)(2*blk+1)*8192 + l15*8;
  const int sw_r = (l15 & 7) << 4;

  bf8v ax0 = *reinterpret_cast<const bf8v*>(xf0);
  bf8v ax1 = *reinterpret_cast<const bf8v*>(xf1);

#define GSTEP(P, T)                                                           \
  {                                                                           \
    int tn = (T) + 1; if (tn > 63) tn = 63;                                   \
    bf8v axn0 = *reinterpret_cast<const bf8v*>(xf0 + tn*128);                 \
    bf8v axn1 = *reinterpret_cast<const bf8v*>(xf1 + tn*128);                 \
    bf8v ah0[4], ah1[4];                                                      \
    _Pragma("unroll")                                                         \
    for (int kb = 0; kb < 4; ++kb){                                           \
      int off = l15*256 + ((kb*64 + lhi*16) ^ sw_r);                          \
      ah0[kb] = *reinterpret_cast<const bf8v*>((const char*)h_lds[0][P] + off); \
      ah1[kb] = *reinterpret_cast<const bf8v*>((const char*)h_lds[1][P] + off); \
    }                                                                         \
    f4v xg0[3], gh0[3], xg1[3], gh1[3];                                       \
    _Pragma("unroll")                                                         \
    for (int g = 0; g < 3; ++g){                                              \
      xg0[g] = splat4(b2v[g]); xg0[g] = mfma16(ax0, w2v[g], xg0[g]);          \
      xg1[g] = splat4(b2v[g]); xg1[g] = mfma16(ax1, w2v[g], xg1[g]);          \
      gh0[g] = splat4(bhv[g]); gh1[g] = splat4(bhv[g]);                       \
      _Pragma("unroll")                                                       \
      for (int kb = 0; kb < 4; ++kb){                                         \
        gh0[g] = mfma16(ah0[kb], bhh[kb][g], gh0[g]);                         \
        gh1[g] = mfma16(ah1[kb], bhh[kb][g], gh1[g]);                         \
      }                                                                       \
    }                                                                         \
    _Pragma("unroll")                                                         \
    for (int r = 0; r < 4; ++r){                                              \
      int s = lhi*4 + r;                                                      \
      int woff = s*256 + (((w*16 + l15)*2) ^ ((s&7)<<4));                     \
      { float rg = sigm(xg0[0][r] + gh0[0][r]);                               \
        float zg = sigm(xg0[1][r] + gh0[1][r]);                               \
        float ng = tanh_(xg0[2][r] + rg*gh0[2][r]);                           \
        float hv = ng + zg*(hr0[r] - ng); hr0[r] = hv;                        \
        *(short*)((char*)h_lds[0][P^1] + woff) = f2bf(hv); }                  \
      { float rg = sigm(xg1[0][r] + gh1[0][r]);                               \
        float zg = sigm(xg1[1][r] + gh1[1][r]);                               \
        float ng = tanh_(xg1[2][r] + rg*gh1[2][r]);                           \
        float hv = ng + zg*(hr1[r] - ng); hr1[r] = hv;                        \
        *(short*)((char*)h_lds[1][P^1] + woff) = f2bf(hv); }                  \
    }                                                                         \
    ax0 = axn0; ax1 = axn1;                                                   \
    __syncthreads();                                                          \
  }

  for (int tt = 0; tt < 32; ++tt){
    GSTEP(0, 2*tt);
    GSTEP(1, 2*tt + 1);
  }
#undef GSTEP

  #pragma unroll
  for (int r = 0; r < 4; ++r){
    int s = lhi*4 + r;
    h_out[(size_t)((2*blk  )*16 + s)*128 + w*16 + l15] = hr0[r];
    h_out[(size_t)((2*blk+1)*16 + s)*128 + w*16 + l15] = hr1[r];
  }
}

// ---------- feats: one seq (64 rows) per block; gate+val GEMMs + segment partials ----------
// A1 stride 320B, 4-row XOR swizzle; A2 (256B stride, 8-row swizzle) aliased into A1 region.
// NOTE: launch_bounds min-waves must stay <=4: accumulators need ~96 VGPR; 6 forced 40 VGPR -> spill disaster (R3).
__global__ __launch_bounds__(256, 4) void feats_kernel(
    const float* __restrict__ x, const float* __restrict__ h_out,
    const float* __restrict__ pe,
    const short* __restrict__ wcf, const short* __restrict__ wn2f,
    const float* __restrict__ bc, const float* __restrict__ Wg2,
    const float* __restrict__ bg2, const float* __restrict__ bn2,
    float* __restrict__ partials)  // [8192][130] = {max, sumE, sumEV[128]}
{
  __shared__ alignas(16) char AB[64*320];     // A1: 64 x 320B | A2: 64 x 256B (aliased)
  __shared__ alignas(16) float hb[160];       // zero-padded h vector
  __shared__ float gp[2][64];
  __shared__ float gate_arr[64];

  const int tid = threadIdx.x;
  const int w = tid >> 6;
  const int lane = tid & 63;
  const int l15 = lane & 15, lhi = lane >> 4;
  const int seq = blockIdx.x;

  if (tid < 160) hb[tid] = (tid >= 6 && tid < 134) ? h_out[(size_t)seq*128 + tid - 6] : 0.f;
  __syncthreads();

  { // build A1: row m = tid>>2, quarter q = tid&3 (40 cols each)
    int m = tid >> 2, q = tid & 3, k0 = q*40;
    float xr8[8] = {0.f,0.f,0.f,0.f,0.f,0.f,0.f,0.f};
    if (q == 0){
      const float* xr = x + (size_t)(seq*64 + m)*6;
      #pragma unroll
      for (int j = 0; j < 6; ++j) xr8[j] = xr[j];
    }
    const float* per = pe + m*160 + k0;
    const f4v* hb4 = reinterpret_cast<const f4v*>(hb + k0);
    int swm = (m & 3) << 4;
    #pragma unroll
    for (int j = 0; j < 10; ++j){
      f4v v = hb4[j];
      f4v p4 = *reinterpret_cast<const f4v*>(per + 4*j);
      v += p4;
      if (j < 2){
        v[0] += xr8[4*j+0]; v[1] += xr8[4*j+1];
        v[2] += xr8[4*j+2]; v[3] += xr8[4*j+3];
      }
      s4v o;
      #pragma unroll
      for (int c = 0; c < 4; ++c) o[c] = f2bf(v[c]);
      int off = m*320 + (((k0 + 4*j)*2) ^ swm);
      *reinterpret_cast<s4v*>(AB + off) = o;
    }
  }
  __syncthreads();

  // GEMM1: hidden(64x256) = A1(64x160) @ Wc(160x256) + bc ; wave w -> nt ntb..ntb+3
  const int ntb = w*4;
  float bcv[4];
  #pragma unroll
  for (int i=0;i<4;++i) bcv[i] = bc[(ntb+i)*16 + l15];
  f4v acc[4][4];
  #pragma unroll
  for (int mt=0;mt<4;++mt)
    #pragma unroll
    for (int i=0;i<4;++i) acc[mt][i] = splat4(bcv[i]);
  #pragma unroll
  for (int kb = 0; kb < 5; ++kb){
    bf8v a[4];
    #pragma unroll
    for (int mt=0;mt<4;++mt){
      int row = l15 + 16*mt;
      int off = row*320 + ((kb*64 + lhi*16) ^ ((row&3)<<4));
      a[mt] = *reinterpret_cast<const bf8v*>(AB + off);
    }
    bf8v b[4];
    #pragma unroll
    for (int i=0;i<4;++i)
      b[i] = *reinterpret_cast<const bf8v*>(wcf + (((kb*16 + ntb + i)*64 + lane)<<3));
    #pragma unroll
    for (int mt=0;mt<4;++mt)
      #pragma unroll
      for (int i=0;i<4;++i) acc[mt][i] = mfma16(a[mt], b[i], acc[mt][i]);
  }
  __syncthreads();   // all A1 reads complete (A2 will overwrite this region)

  // phase 2: waves 0,1 -> gate partials (in-wave reduce); waves 2,3 -> silu into A2
  if (w < 2){
    float wg2v[4];
    #pragma unroll
    for (int i=0;i<4;++i) wg2v[i] = Wg2[(ntb+i)*16 + l15];
    #pragma unroll
    for (int mt=0;mt<4;++mt)
      #pragma unroll
      for (int r=0;r<4;++r){
        float p = 0.f;
        #pragma unroll
        for (int i=0;i<4;++i){ float v = acc[mt][i][r]; p += v*sigm(v)*wg2v[i]; }
        p += __shfl_xor(p, 1); p += __shfl_xor(p, 2);
        p += __shfl_xor(p, 4); p += __shfl_xor(p, 8);
        if (l15 == 0) gp[w][mt*16 + lhi*4 + r] = p;
      }
  } else {
    #pragma unroll
    for (int mt=0;mt<4;++mt)
      #pragma unroll
      for (int i=0;i<4;++i)
        #pragma unroll
        for (int r=0;r<4;++r){
          float v = acc[mt][i][r]; float s = v*sigm(v);
          int row = mt*16 + lhi*4 + r;
          int colb = (((w-2)*4 + i)*16 + l15)*2;
          int off = row*256 + (colb ^ ((row&7)<<4));
          *(short*)(AB + off) = f2bf(s);
        }
  }
  __syncthreads();   // A2 + gp visible

  if (tid < 64) gate_arr[tid] = bg2[0] + gp[0][tid] + gp[1][tid];

  // GEMM2: val(64x128) = A2(64x128) @ Wn2 + bn2 ; wave w -> nt2 {2w,2w+1}
  const int nt2b = w*2;
  float bn2v[2];
  #pragma unroll
  for (int i=0;i<2;++i) bn2v[i] = bn2[(nt2b+i)*16 + l15];
  f4v acc2[4][2];
  #pragma unroll
  for (int mt=0;mt<4;++mt)
    #pragma unroll
    for (int i=0;i<2;++i) acc2[mt][i] = splat4(bn2v[i]);
  #pragma unroll
  for (int kb = 0; kb < 4; ++kb){
    bf8v a2f[4];
    #pragma unroll
    for (int mt=0;mt<4;++mt){
      int row = l15 + 16*mt;
      int off = row*256 + ((kb*64 + lhi*16) ^ ((row&7)<<4));
      a2f[mt] = *reinterpret_cast<const bf8v*>(AB + off);
    }
    bf8v b2f[2];
    #pragma unroll
    for (int i=0;i<2;++i)
      b2f[i] = *reinterpret_cast<const bf8v*>(wn2f + (((kb*8 + nt2b + i)*64 + lane)<<3));
    #pragma unroll
    for (int mt=0;mt<4;++mt)
      #pragma unroll
      for (int i=0;i<2;++i) acc2[mt][i] = mfma16(a2f[mt], b2f[i], acc2[mt][i]);
  }
  __syncthreads();  // gate_arr ready

  // phase 4: block-local softmax partials (exact flash combine)
  float g = gate_arr[lane];
  float M = g;
  #pragma unroll
  for (int d=1; d<64; d<<=1) M = fmaxf(M, __shfl_xor(M, d));
  float e = ex2((g - M)*L2E);
  float sE = e;
  #pragma unroll
  for (int d=1; d<64; d<<=1) sE += __shfl_xor(sE, d);
  float ev0 = 0.f, ev1 = 0.f;
  #pragma unroll
  for (int mt=0;mt<4;++mt)
    #pragma unroll
    for (int r=0;r<4;++r){
      int row = mt*16 + lhi*4 + r;
      float wm = ex2((gate_arr[row] - M)*L2E);
      ev0 += wm*acc2[mt][0][r];
      ev1 += wm*acc2[mt][1][r];
    }
  ev0 += __shfl_xor(ev0, 16); ev0 += __shfl_xor(ev0, 32);
  ev1 += __shfl_xor(ev1, 16); ev1 += __shfl_xor(ev1, 32);

  float* pb = partials + (size_t)seq*130;
  if (tid == 0){ pb[0] = M; pb[1] = sE; }
  if (lane < 16){
    pb[2 + (nt2b+0)*16 + lane] = ev0;
    pb[2 + (nt2b+1)*16 + lane] = ev1;
  }
}

// ---------- combine: merge 64 partials per batch ----------
__global__ void combine_kernel(const float* __restrict__ partials, float* __restrict__ out)
{
  int b = blockIdx.x; int j = threadIdx.x;  // 128 threads
  const float* pb = partials + (size_t)b*64*130;
  float M = -3.0e38f;
  for (int p = 0; p < 64; ++p) M = fmaxf(M, pb[p*130]);
  float num = 0.f, den = 0.f;
  for (int p = 0; p < 64; ++p){
    float wm = ex2((pb[p*130] - M)*L2E);
    den += wm * pb[p*130 + 1];
    num += wm * pb[p*130 + 2 + j];
  }
  out[b*128 + j] = num / den;
}

// ---------- host ----------
extern "C" void kernel_launch(void* const* d_in, const int* in_sizes, int n_in,
                              void* d_out, int out_size, void* d_ws, size_t ws_size,
                              hipStream_t stream) {
  (void)in_sizes; (void)n_in; (void)out_size; (void)ws_size;
  const float* x     = (const float*)d_in[0];
  const float* W_emb = (const float*)d_in[1];
  const float* b_emb = (const float*)d_in[2];
  const float* W_ih  = (const float*)d_in[3];
  const float* W_hh  = (const float*)d_in[4];
  const float* b_ih  = (const float*)d_in[5];
  const float* b_hh  = (const float*)d_in[6];
  const float* Wg1   = (const float*)d_in[7];
  const float* bg1   = (const float*)d_in[8];
  const float* Wg2   = (const float*)d_in[9];
  const float* bg2   = (const float*)d_in[10];
  const float* Wn1   = (const float*)d_in[11];
  const float* bn1   = (const float*)d_in[12];
  const float* Wn2   = (const float*)d_in[13];
  const float* bn2   = (const float*)d_in[14];

  char* p = (char*)d_ws;
  short* bhhf = (short*)p; p += 98304;
  short* wcf  = (short*)p; p += 81920;
  short* wn2f = (short*)p; p += 32768;
  short* w2f  = (short*)p; p += 24576;
  float* b2   = (float*)p; p += 1536;
  float* pe   = (float*)p; p += 40960;
  float* bc   = (float*)p; p += 1024;
  short* xfrag = (short*)p; p += (size_t)524288*8*2;     // 8.4 MB
  float* h_out    = (float*)p; p += (size_t)8192*128*4;
  float* partials = (float*)p; p += (size_t)8192*130*4;

  prep_kernel<<<2555, 256, 0, stream>>>(x, W_emb, b_emb, W_ih, W_hh, b_ih,
                                        Wg1, Wn1, Wn2, bg1, bn1,
                                        bhhf, wcf, wn2f, w2f, b2, pe, bc, xfrag);
  gru_kernel<<<256, 512, 0, stream>>>(xfrag, bhhf, w2f, b2, b_hh, h_out);
  feats_kernel<<<8192, 256, 0, stream>>>(x, h_out, pe, wcf, wn2f, bc, Wg2, bg2, bn2, partials);
  combine_kernel<<<128, 128, 0, stream>>>(partials, (float*)d_out);
}